// Round 1
// 363.990 us; speedup vs baseline: 1.0200x; 1.0200x over previous
//
#include <hip/hip_runtime.h>

// Problem dims (fixed by reference): P=64, CIN=16 (z), COUT=16 (v), T=4 (a/b), N=32 (i,j), X=64
#define NP    64
#define NCIN  16
#define NCOUT 16
#define NT    4
#define NN    32
#define NX    64

typedef __attribute__((ext_vector_type(8))) __bf16 bf16x8;
typedef __attribute__((ext_vector_type(4))) float  f32x4;

// pack two fp32 -> packed bf16 pair (round-half-up via +0x8000, then take high 16 bits)
__device__ __forceinline__ unsigned pk_bf16(float lo, float hi) {
    unsigned ulo = __float_as_uint(lo) + 0x8000u;
    unsigned uhi = __float_as_uint(hi) + 0x8000u;
    return __builtin_amdgcn_perm(uhi, ulo, 0x07060302u);
}

// Block = (p, i): 256 threads = 4 waves; wave w handles j = w*8 .. w*8+7.
// Stage 1 (per atom): Q[z,ab] = sum_x FW[z,x] * (PFi[a,x]*PFj[b,x]) via 2x mfma 16x16x32 bf16.
//   Q is written to LDS as bf16 hi + bf16 residual lo (split precision ~ fp32-equivalent).
// Stage 2 (per wave, once): out[v,j] = sum_{k=ab*16+z, 256 terms} WW2[v,k] * Q[k,j]
//   as 16x mfma 16x16x32 bf16 (8 k-chunks x {hi,lo} planes), A = WW2 bf16 from LDS.
// This replaces the old per-lane 64-FMA contraction + 17-step butterfly reduce per atom.
__global__ __launch_bounds__(256, 2) void higher_point_kernel(
    const float* __restrict__ FW,   // (P, CIN, N, N, X)
    const float* __restrict__ PF,   // (P, T, N, X)
    const float* __restrict__ W0,   // (T, CIN, COUT)
    const float* __restrict__ W1,   // (T, CIN, COUT)
    const float* __restrict__ BIAS, // (COUT,1,1)
    float* __restrict__ OUT)        // (P, COUT, N, N)
{
    __shared__ __align__(16) float pf_lds[NT * NN * NX];        // 32 KB, PF[p] staged [t][j][x]
    __shared__ __align__(16) unsigned short ww_lds[16 * 256];   // 8 KB:  [v][k=ab*16+z] bf16, XOR-swizzled
    __shared__ __align__(16) unsigned short q_lds[4][8 * 512];  // 32 KB: [wave][jj][plane*256+k] bf16, swizzled

    const int bx   = blockIdx.x;
    const int p    = bx >> 5;
    const int i    = bx & 31;
    const int tid  = threadIdx.x;
    const int lane = tid & 63;
    const int wave = tid >> 6;

    // ---- stage PF[p] (8192 floats) into LDS, coalesced float4 ----
    {
        const float4* pf_g = (const float4*)(PF + p * (NT * NN * NX));
        float4* pf_s = (float4*)pf_lds;
        #pragma unroll
        for (int k = 0; k < 8; ++k) pf_s[tid + k * 256] = pf_g[tid + k * 256];
    }

    // ---- WW2 -> LDS: thread (v=tid>>4, ab=tid&15) computes WW[z,ab,v]=W0[a,z,v]*W1[b,z,v]
    //      for z=0..15, packs bf16, writes row v at k=ab*16+z, byte offset XOR ((v&7)<<4) ----
    {
        const int v  = tid >> 4;
        const int ab = tid & 15;
        const int a  = ab >> 2, b = ab & 3;
        float prod[16];
        #pragma unroll
        for (int z = 0; z < 16; ++z)
            prod[z] = W0[(a * NCIN + z) * NCOUT + v] * W1[(b * NCIN + z) * NCOUT + v];
        unsigned pw[8];
        #pragma unroll
        for (int t = 0; t < 8; ++t) pw[t] = pk_bf16(prod[2 * t], prod[2 * t + 1]);
        char* base = (char*)ww_lds + v * 512;
        const int swz = (v & 7) << 4;
        *(uint4*)(base + ((ab * 32) ^ swz))      = make_uint4(pw[0], pw[1], pw[2], pw[3]);
        *(uint4*)(base + ((ab * 32 + 16) ^ swz)) = make_uint4(pw[4], pw[5], pw[6], pw[7]);
    }
    __syncthreads();

    const int c = lane & 15;  // A-frag row (z) / B-frag col (ab) / D col (ab)
    const int q = lane >> 4;  // quad: k-block for A/B frags, row-block for D
    const int aIdx = c >> 2;  // ab = a*4 + b
    const int bIdx = c & 3;

    // ---- PF_i slice (fixed per block): a=aIdx, x = q*8+e (half0) / +32 (half1) ----
    float pfi0[8], pfi1[8];
    {
        const float* base = pf_lds + (aIdx * NN + i) * NX + q * 8;
        #pragma unroll
        for (int e = 0; e < 8; ++e) { pfi0[e] = base[e]; pfi1[e] = base[32 + e]; }
    }

    // ---- FW row base for this lane: z = c, lane's x-offset q*8 ----
    const float* fw_row = FW + ((p * NCIN + c) * (NN * NN) + i * NN) * NX + q * 8;

    const int j0 = wave * 8;

    // software-pipelined FW loads (4 x dwordx4 per atom per lane = the whole HBM stream)
    float4 nf0a, nf0b, nf1a, nf1b;
    {
        const float* rb = fw_row + j0 * NX;
        nf0a = ((const float4*)rb)[0];
        nf0b = ((const float4*)rb)[1];
        nf1a = ((const float4*)(rb + 32))[0];
        nf1b = ((const float4*)(rb + 32))[1];
    }

    for (int jj = 0; jj < 8; ++jj) {
        const int j = j0 + jj;
        float4 f0a = nf0a, f0b = nf0b, f1a = nf1a, f1b = nf1b;
        if (jj < 7) {
            const float* rb = fw_row + (j + 1) * NX;
            nf0a = ((const float4*)rb)[0];
            nf0b = ((const float4*)rb)[1];
            nf1a = ((const float4*)(rb + 32))[0];
            nf1b = ((const float4*)(rb + 32))[1];
        }

        // PF_j slice from LDS: b=bIdx, x = q*8+e (+32)
        float pfj0[8], pfj1[8];
        {
            const float* base = pf_lds + (bIdx * NN + j) * NX + q * 8;
            #pragma unroll
            for (int e = 0; e < 8; ++e) { pfj0[e] = base[e]; pfj1[e] = base[32 + e]; }
        }

        // A-frags: FW[z=c][x=q*8+e]  (halves x:0..31 / 32..63)
        union { unsigned u[4]; bf16x8 v; } A0, A1, B0, B1;
        A0.u[0] = pk_bf16(f0a.x, f0a.y); A0.u[1] = pk_bf16(f0a.z, f0a.w);
        A0.u[2] = pk_bf16(f0b.x, f0b.y); A0.u[3] = pk_bf16(f0b.z, f0b.w);
        A1.u[0] = pk_bf16(f1a.x, f1a.y); A1.u[1] = pk_bf16(f1a.z, f1a.w);
        A1.u[2] = pk_bf16(f1b.x, f1b.y); A1.u[3] = pk_bf16(f1b.z, f1b.w);

        // B-frags: R[ab=c][x=q*8+e] = PFi[a,x]*PFj[b,x]
        float r0[8], r1[8];
        #pragma unroll
        for (int e = 0; e < 8; ++e) { r0[e] = pfi0[e] * pfj0[e]; r1[e] = pfi1[e] * pfj1[e]; }
        B0.u[0] = pk_bf16(r0[0], r0[1]); B0.u[1] = pk_bf16(r0[2], r0[3]);
        B0.u[2] = pk_bf16(r0[4], r0[5]); B0.u[3] = pk_bf16(r0[6], r0[7]);
        B1.u[0] = pk_bf16(r1[0], r1[1]); B1.u[1] = pk_bf16(r1[2], r1[3]);
        B1.u[2] = pk_bf16(r1[4], r1[5]); B1.u[3] = pk_bf16(r1[6], r1[7]);

        // Q[z,ab] accumulate (fp32 C-regs). D: col = lane&15 = ab, row z = q*4 + reg.
        f32x4 acc = {0.f, 0.f, 0.f, 0.f};
        acc = __builtin_amdgcn_mfma_f32_16x16x32_bf16(A0.v, B0.v, acc, 0, 0, 0);
        acc = __builtin_amdgcn_mfma_f32_16x16x32_bf16(A1.v, B1.v, acc, 0, 0, 0);

        // ---- Q -> LDS, bf16 hi + residual lo (split precision). Lane holds
        //      Q[z=q*4+r][ab=c] -> row jj, k = c*16 + q*4 + r, bytes XOR (jj<<4). ----
        unsigned ua0 = __float_as_uint(acc[0]) + 0x8000u;
        unsigned ua1 = __float_as_uint(acc[1]) + 0x8000u;
        unsigned ua2 = __float_as_uint(acc[2]) + 0x8000u;
        unsigned ua3 = __float_as_uint(acc[3]) + 0x8000u;
        unsigned qhi01 = __builtin_amdgcn_perm(ua1, ua0, 0x07060302u);
        unsigned qhi23 = __builtin_amdgcn_perm(ua3, ua2, 0x07060302u);
        float l0 = acc[0] - __uint_as_float(ua0 & 0xffff0000u);
        float l1 = acc[1] - __uint_as_float(ua1 & 0xffff0000u);
        float l2 = acc[2] - __uint_as_float(ua2 & 0xffff0000u);
        float l3 = acc[3] - __uint_as_float(ua3 & 0xffff0000u);
        unsigned qlo01 = pk_bf16(l0, l1);
        unsigned qlo23 = pk_bf16(l2, l3);

        char* qrow = (char*)q_lds[wave] + jj * 1024 + ((c * 32 + q * 8) ^ (jj << 4));
        *(uint2*)(qrow)       = make_uint2(qhi01, qhi23);  // hi plane (k' = k)
        *(uint2*)(qrow + 512) = make_uint2(qlo01, qlo23);  // lo plane (k' = 256 + k)
    }
    __syncthreads();

    // ---- Stage 2: out[v, j] = sum_k WW2[v,k] * Q[k,j], k = ab*16+z (256) x {hi,lo}.
    //      A lane: WW2[v=c][k = m*32 + q*8 + e];  B lane: Q[k][j=c] (rows 8..15 alias 0..7,
    //      cols c>=8 are discarded).  D: row v = q*4+r, col j = c. ----
    const int swzc = (c & 7) << 4;
    const char* wwbase = (const char*)ww_lds + c * 512;
    const char* qbase  = (const char*)q_lds[wave] + (c & 7) * 1024;
    const int qoff = q * 16;

    uint4 aw[8];
    #pragma unroll
    for (int m = 0; m < 8; ++m)
        aw[m] = *(const uint4*)(wwbase + ((m * 64 + qoff) ^ swzc));

    f32x4 acc2 = {0.f, 0.f, 0.f, 0.f};
    #pragma unroll
    for (int pl = 0; pl < 2; ++pl) {
        #pragma unroll
        for (int m = 0; m < 8; ++m) {
            union { uint4 u; bf16x8 v; } av, qb;
            av.u = aw[m];
            qb.u = *(const uint4*)(qbase + pl * 512 + ((m * 64 + qoff) ^ swzc));
            acc2 = __builtin_amdgcn_mfma_f32_16x16x32_bf16(av.v, qb.v, acc2, 0, 0, 0);
        }
    }

    // ---- epilogue: lane (c<8, q) holds out[v=q*4+r][j=j0+c] ----
    if (c < 8) {
        const int j = j0 + c;
        const float4 b4 = *(const float4*)(BIAS + q * 4);
        float bb[4] = {b4.x, b4.y, b4.z, b4.w};
        float* op = OUT + (p * NCOUT * NN + i) * NN + j;
        #pragma unroll
        for (int r = 0; r < 4; ++r) {
            float rv = acc2[r] + bb[r];
            rv = rv > 0.f ? rv : 0.f;
            op[(q * 4 + r) * (NN * NN)] = rv;
        }
    }
}

extern "C" void kernel_launch(void* const* d_in, const int* in_sizes, int n_in,
                              void* d_out, int out_size, void* d_ws, size_t ws_size,
                              hipStream_t stream) {
    const float* FW   = (const float*)d_in[0]; // features_weighted (P,CIN,N,N,X)
    const float* PF   = (const float*)d_in[1]; // pair_features (P,T,N,X)
    const float* W0   = (const float*)d_in[2]; // (T,CIN,COUT)
    const float* W1   = (const float*)d_in[3]; // (T,CIN,COUT)
    const float* BIAS = (const float*)d_in[4]; // (COUT,1,1)
    float* OUT = (float*)d_out;                // (P,COUT,N,N)

    hipLaunchKernelGGL(higher_point_kernel, dim3(NP * NN), dim3(256), 0, stream,
                       FW, PF, W0, W1, BIAS, OUT);
}